// Round 3
// baseline (393.753 us; speedup 1.0000x reference)
//
#include <hip/hip_runtime.h>

#define BB      8192
#define KK      50
#define NGLOB   16384
#define INV_T   0.5f
// TEMP^2 / B
#define OUTSCALE (4.0f / 8192.0f)

__global__ __launch_bounds__(256) void g2l_init_kernel(int* __restrict__ g2l, int cap) {
    int i = blockIdx.x * 256 + threadIdx.x;
    if (i < cap) g2l[i] = -1;
}

__global__ __launch_bounds__(256) void g2l_fill_kernel(int* __restrict__ g2l,
                                                       const int* __restrict__ bidx,
                                                       int n, int cap) {
    int i = blockIdx.x * 256 + threadIdx.x;
    if (i < n) {
        int g = bidx[i];
        if (g >= 0 && g < cap) g2l[g] = i;   // JAX drops OOB scatter updates
    }
}

__global__ __launch_bounds__(256) void distill_loss_kernel(
        const float* __restrict__ logits,
        const int*   __restrict__ tidx,
        const float* __restrict__ tsc,
        const int*   __restrict__ g2l,
        int          g2l_cap,
        float*       __restrict__ out)
{
    __shared__ float trow[BB];        // dense target row, 32 KB
    __shared__ float wred[4];         // cross-wave scalar reduce
    __shared__ float wred3[3][4];     // final 3-value reduce

    const int row  = blockIdx.x;
    const int tid  = threadIdx.x;
    const int lane = tid & 63;
    const int wave = tid >> 6;

    // ---- prefetch teacher entry + g2l gather early (hides pointer-chase
    //      latency under the softmax reductions below) ----
    int   my_local = -1;
    float my_score = 0.0f;
    if (tid < KK) {
        int g = tidx[row * KK + tid];
        my_score = tsc[row * KK + tid];
        if ((unsigned)g < (unsigned)g2l_cap) my_local = g2l[g];
    }

    // ---- single-pass load of this row into registers (coalesced float4) ----
    const float4* lrow = (const float4*)(logits + (size_t)row * BB);
    float x[32];
    #pragma unroll
    for (int c = 0; c < 8; ++c) {
        float4 v = lrow[c * 256 + tid];
        x[c * 4 + 0] = v.x;
        x[c * 4 + 1] = v.y;
        x[c * 4 + 2] = v.z;
        x[c * 4 + 3] = v.w;
    }

    // ---- zero the dense target row ----
    #pragma unroll
    for (int c = 0; c < 32; ++c) trow[c * 256 + tid] = 0.0f;

    // ---- row max of raw logits ----
    float m = x[0];
    #pragma unroll
    for (int j = 1; j < 32; ++j) m = fmaxf(m, x[j]);
    #pragma unroll
    for (int off = 32; off >= 1; off >>= 1)
        m = fmaxf(m, __shfl_xor(m, off, 64));
    if (lane == 0) wred[wave] = m;
    __syncthreads();                  // also guarantees trow fully zeroed
    m = fmaxf(fmaxf(wred[0], wred[1]), fmaxf(wred[2], wred[3]));

    // ---- sum of exp((x - m) / T) ----
    float se = 0.0f;
    #pragma unroll
    for (int j = 0; j < 32; ++j) se += __expf((x[j] - m) * INV_T);
    #pragma unroll
    for (int off = 32; off >= 1; off >>= 1)
        se += __shfl_xor(se, off, 64);
    __syncthreads();                  // protect wred reuse
    if (lane == 0) wred[wave] = se;
    __syncthreads();
    se = wred[0] + wred[1] + wred[2] + wred[3];
    const float logZ = m * INV_T + logf(se);

    // ---- scatter prefetched teacher scores (set semantics; dup race is
    //      negligible: expected rel. err ~1e-4 on the scalar loss) ----
    if (my_local >= 0 && my_local < BB) trow[my_local] = my_score;
    __syncthreads();
    if (tid == 0) trow[row] = 1.0f;   // diag override AFTER scatter, like ref
    __syncthreads();

    // ---- scan dense row vs register logits ----
    float S = 0.0f, A = 0.0f, C = 0.0f;
    #pragma unroll
    for (int c = 0; c < 8; ++c) {
        float4 r4 = ((const float4*)trow)[c * 256 + tid];
        float rr[4] = { r4.x, r4.y, r4.z, r4.w };
        #pragma unroll
        for (int q = 0; q < 4; ++q) {
            float r = rr[q];
            if (r > 0.0f) {
                S += r;
                A += r * logf(r);
                C += r * (x[c * 4 + q] * INV_T);
            }
        }
    }

    // ---- block reduce (S, A, C) ----
    #pragma unroll
    for (int off = 32; off >= 1; off >>= 1) {
        S += __shfl_xor(S, off, 64);
        A += __shfl_xor(A, off, 64);
        C += __shfl_xor(C, off, 64);
    }
    if (lane == 0) {
        wred3[0][wave] = S;
        wred3[1][wave] = A;
        wred3[2][wave] = C;
    }
    __syncthreads();
    if (tid == 0) {
        S = wred3[0][0] + wred3[0][1] + wred3[0][2] + wred3[0][3];
        A = wred3[1][0] + wred3[1][1] + wred3[1][2] + wred3[1][3];
        C = wred3[2][0] + wred3[2][1] + wred3[2][2] + wred3[2][3];
        // row loss = sum_j t_j*(log t_j - logp_j), t = r/S, logp = x/T - logZ
        float rl = (A - C) / S + logZ - logf(S);
        atomicAdd(out, rl * OUTSCALE);
    }
}

extern "C" void kernel_launch(void* const* d_in, const int* in_sizes, int n_in,
                              void* d_out, int out_size, void* d_ws, size_t ws_size,
                              hipStream_t stream) {
    const float* logits = (const float*)d_in[0];
    const int*   bidx   = (const int*)d_in[1];
    const int*   tidx   = (const int*)d_in[2];
    const float* tsc    = (const float*)d_in[3];
    float* out = (float*)d_out;
    int*   g2l = (int*)d_ws;

    const int Bn = in_sizes[1];       // 8192

    // Defensive: never write past the provided workspace. For this problem
    // ws_size should be >= 64 KB; cap degrades gracefully instead of crashing.
    int cap = NGLOB;
    size_t need = (size_t)NGLOB * sizeof(int);
    if (ws_size < need) cap = (int)(ws_size / sizeof(int));

    hipMemsetAsync(d_out, 0, (size_t)out_size * sizeof(float), stream);
    if (cap > 0) {
        g2l_init_kernel<<<(cap + 255) / 256, 256, 0, stream>>>(g2l, cap);
        g2l_fill_kernel<<<(Bn + 255) / 256, 256, 0, stream>>>(g2l, bidx, Bn, cap);
    }
    distill_loss_kernel<<<Bn, 256, 0, stream>>>(logits, tidx, tsc, g2l, cap, out);
}